// Round 14
// baseline (408.523 us; speedup 1.0000x reference)
//
#include <hip/hip_runtime.h>
#include <cmath>

constexpr int BN = 16, CN = 64, HN = 256, WN = 256;
constexpr int IMG = HN * WN;
constexpr float EPSF = 0.001f;

typedef short bf16x8 __attribute__((ext_vector_type(8)));
typedef float f32x4  __attribute__((ext_vector_type(4)));

// ---- bf16 helpers (RNE, finite inputs) ------------------------------------
__device__ __forceinline__ unsigned short f2bf(float f) {
    unsigned u = __builtin_bit_cast(unsigned, f);
    u += 0x7fffu + ((u >> 16) & 1u);
    return (unsigned short)(u >> 16);
}
__device__ __forceinline__ float bf2f(unsigned short h) {
    return __builtin_bit_cast(float, ((unsigned)h) << 16);
}

__device__ __forceinline__ void gload16(const void* g, void* l) {
    __builtin_amdgcn_global_load_lds(
        (const __attribute__((address_space(1))) unsigned int*)g,
        (__attribute__((address_space(3))) unsigned int*)l, 16, 0, 0);
}

// ---------------------------------------------------------------------------
// Weight prep: W[co][ci][3][3] fp32 -> bf16 MFMA A-fragments
// ---------------------------------------------------------------------------
__global__ __launch_bounds__(256)
void k_wprep(const float* __restrict__ w, unsigned short* __restrict__ wp) {
    int flat = blockIdx.x * 256 + threadIdx.x;       // 0..36863
    int ct = flat / 9216;
    int r1 = flat % 9216;
    int s  = r1 / 1024;
    int r2 = r1 % 1024;
    int kk = r2 >> 9;
    int l  = (r2 >> 3) & 63;
    int e  = r2 & 7;
    int co = ct * 16 + (l & 15);
    int ci = kk * 32 + (l >> 4) * 8 + e;
    int kh = s / 3, kw = s % 3;
    wp[flat] = f2bf(w[((co * 64 + ci) * 3 + kh) * 3 + kw]);
}

// ---------------------------------------------------------------------------
// Pass 0: x[b][c][i][j] fp32 -> xT[b][i][j][c] bf16  (pure layout transpose)
// ---------------------------------------------------------------------------
__global__ __launch_bounds__(256)
void k_xpose(const float* __restrict__ x, unsigned short* __restrict__ xT) {
    __shared__ alignas(16) unsigned char sm[WN * CN * 2];   // 32 KB [j][c]
    const int j = threadIdx.x;
    const int i = blockIdx.x;
    const int b = blockIdx.y;
    const float* xb = x + (size_t)b * CN * IMG + (size_t)i * WN + j;
#pragma unroll 2
    for (int c0 = 0; c0 < CN; c0 += 8) {
        unsigned short p[8];
#pragma unroll
        for (int e = 0; e < 8; ++e)
            p[e] = f2bf(xb[(size_t)(c0 + e) * IMG]);
        int byte = (j << 7) + (c0 << 1);
        byte ^= (j & 7) << 4;                 // bank swizzle
        *(uint4*)(sm + byte) = *(const uint4*)p;
    }
    __syncthreads();
    char* dst = (char*)xT + (size_t)(b * HN + i) * (WN * CN * 2);
#pragma unroll
    for (int k = 0; k < 8; ++k) {
        int u = k * 256 + threadIdx.x;
        int jj = u >> 3, ch = u & 7;
        int byte = (jj << 7) + ((ch ^ (jj & 7)) << 4);
        *(uint4*)(dst + (size_t)u * 16) = *(const uint4*)(sm + byte);
    }
}

// ---------------------------------------------------------------------------
// Pass 1: xT -> lpT (log-polar gather). Block = 16 j x 16 groups of 4 ch.
// Wave 0 precomputes per-pixel bilinear weights (validity folded) + offsets.
// ---------------------------------------------------------------------------
__global__ __launch_bounds__(256)
void k_c2lp(const unsigned short* __restrict__ xT, unsigned short* __restrict__ lpT,
            float lr_scale, float th_scale) {
    __shared__ alignas(16) float sw[16][4];
    __shared__ alignas(16) int   so[16][4];
    const int tid = threadIdx.x;
    const int g   = tid & 15;              // channel group (4 ch)
    const int jl  = tid >> 4;              // 0..15
    const int j0  = blockIdx.x * 16;
    const int j   = j0 + jl;
    const int i   = blockIdx.y;
    const int b   = blockIdx.z;
    const int c0  = g * 4;

    if (tid < 16) {
        float r  = __expf((float)(j0 + tid) * lr_scale);
        float th = (float)i * th_scale;
        float gx = fmaf(r, cosf(th), 127.5f);
        float gy = fmaf(r, sinf(th), 127.5f);
        float left = floorf(gx), top = floorf(gy);
        int li = (int)left, ti = (int)top, ri = li + 1, bi = ti + 1;
        float dl = gx - left, dr = left + 1.0f - gx;
        float dt = gy - top,  db = top + 1.0f - gy;
        bool vl = (unsigned)li < (unsigned)WN, vr = (unsigned)ri < (unsigned)WN;
        bool vt = (unsigned)ti < (unsigned)HN, vb = (unsigned)bi < (unsigned)HN;
        bool v0 = vl && vt, v1 = vr && vt, v2 = vl && vb, v3 = vr && vb;
        sw[tid][0] = v0 ? db * dr : 0.0f;
        sw[tid][1] = v1 ? db * dl : 0.0f;
        sw[tid][2] = v2 ? dt * dr : 0.0f;
        sw[tid][3] = v3 ? dt * dl : 0.0f;
        so[tid][0] = v0 ? (ti * WN + li) * CN : 0;
        so[tid][1] = v1 ? (ti * WN + ri) * CN : 0;
        so[tid][2] = v2 ? (bi * WN + li) * CN : 0;
        so[tid][3] = v3 ? (bi * WN + ri) * CN : 0;
    }
    __syncthreads();
    f32x4 w4 = *(const f32x4*)sw[jl];
    int4  o4 = *(const int4*)so[jl];

    const unsigned short* yb = xT + (size_t)b * IMG * CN + c0;
    union U4 { uint2 u; unsigned short s[4]; };
    U4 tl, tr, bl, br;
    tl.u = *(const uint2*)(yb + o4.x);
    tr.u = *(const uint2*)(yb + o4.y);
    bl.u = *(const uint2*)(yb + o4.z);
    br.u = *(const uint2*)(yb + o4.w);

    U4 res;
#pragma unroll
    for (int e = 0; e < 4; ++e) {
        float v = w4[0] * bf2f(tl.s[e]) + w4[1] * bf2f(tr.s[e])
                + w4[2] * bf2f(bl.s[e]) + w4[3] * bf2f(br.s[e]);
        res.s[e] = f2bf(v);
    }
    *(uint2*)(lpT + ((size_t)(b * HN + i) * WN + j) * CN + c0) = res.u;
}

// ---------------------------------------------------------------------------
// Pass 2: MFMA conv. 1D grid (8192) + bijective XCD swizzle: each XCD owns a
// contiguous (b,i)-band so the 3x row-staging re-reads hit its private L2.
// logical = ((b*256)+i)*2 + jt, jt fastest. Body = round-13 (co-paired MFMA).
// ---------------------------------------------------------------------------
__global__ __launch_bounds__(256)
void k_conv(const unsigned short* __restrict__ lpT,
            const unsigned short* __restrict__ wp,
            const float* __restrict__ bias,
            unsigned short* __restrict__ yT) {
    __shared__ alignas(16) unsigned char sm[3 * 130 * 64 * 2];   // 49920 B
    const int tid = threadIdx.x;
    const int w = tid >> 6, lane = tid & 63;
    const int lanelo = lane & 15, lanehi = lane >> 4;
    const int wcol = (w & 1) * 64;        // this wave's column half
    const int wco  = (w >> 1) * 2;        // this wave's first co-tile (of 16 co)

    // XCD swizzle: phys -> logical so XCD k gets contiguous logical chunk
    const int phys    = blockIdx.x;            // 0..8191
    const int logical = (phys & 7) * 1024 + (phys >> 3);
    const int jt = logical & 1;
    const int i  = (logical >> 1) & 255;
    const int b  = logical >> 9;
    const int j0 = jt * 128;

    // ---- stage 3 rows x 130 cols x 64 ci (3120 16B units) ----
    for (int u0 = 0; u0 < 3120; u0 += 256) {
        int unit = u0 + tid;
        if (unit < 3120) {
            int r   = unit / 1040;
            int rem = unit - r * 1040;
            int col = rem >> 3, ch = rem & 7;
            int ii = i - 1 + r;
            int jj = j0 - 1 + col;
            void* lptr = sm + unit * 16;
            if ((unsigned)ii < 256u && (unsigned)jj < 256u) {
                int sch = ch ^ (col & 7);        // pre-swizzled source
                const unsigned short* g =
                    lpT + (((size_t)(b * 256 + ii) * 256 + jj) * 64 + sch * 8);
                gload16(g, lptr);
            } else {
                uint4 z; z.x = z.y = z.z = z.w = 0;
                *(uint4*)lptr = z;
            }
        }
    }

    // ---- weights: 2 co-tiles x 18 A-fragments ----
    bf16x8 af[2][18];
#pragma unroll
    for (int m = 0; m < 2; ++m)
#pragma unroll
        for (int sk = 0; sk < 18; ++sk)
            af[m][sk] = *(const bf16x8*)(
                wp + ((size_t)((wco + m) * 18 + sk) * 64 + lane) * 8);

    // ---- accumulators (2 co-tiles x 4 col-frags), init with bias ----
    f32x4 acc[2][4];
#pragma unroll
    for (int m = 0; m < 2; ++m) {
        int co_row = (wco + m) * 16 + lanehi * 4;
        f32x4 binit = { bias[co_row], bias[co_row + 1],
                        bias[co_row + 2], bias[co_row + 3] };
#pragma unroll
        for (int n = 0; n < 4; ++n) acc[m][n] = binit;
    }

    __syncthreads();

    // ---- 9 shifts x 2 K-steps x 4 col-frags; each B read feeds 2 MFMAs ----
#pragma unroll
    for (int s = 0; s < 9; ++s) {
        const int kh = s / 3, kw = s % 3;
#pragma unroll
        for (int kk = 0; kk < 2; ++kk) {
            const int cih = kk * 4 + lanehi;        // ci>>3
#pragma unroll
            for (int n = 0; n < 4; ++n) {
                int col  = wcol + n * 16 + lanelo + kw;    // 0..129
                int unit = (kh * 130 + col) * 8 + (cih ^ (col & 7));
                bf16x8 bf = *(const bf16x8*)(sm + unit * 16);
                acc[0][n] = __builtin_amdgcn_mfma_f32_16x16x32_bf16(
                    af[0][s * 2 + kk], bf, acc[0][n], 0, 0, 0);
                acc[1][n] = __builtin_amdgcn_mfma_f32_16x16x32_bf16(
                    af[1][s * 2 + kk], bf, acc[1][n], 0, 0, 0);
            }
        }
    }

    __syncthreads();    // all ds_reads done; reuse sm for out tile [128][64] bf16

#pragma unroll
    for (int m = 0; m < 2; ++m)
#pragma unroll
        for (int n = 0; n < 4; ++n) {
            int col = wcol + n * 16 + lanelo;
            int co  = (wco + m) * 16 + lanehi * 4;
            unsigned short p[4];
#pragma unroll
            for (int r = 0; r < 4; ++r) p[r] = f2bf(acc[m][n][r]);
            int byte = (col << 7) + (co << 1);
            byte ^= (col & 7) << 4;
            *(uint2*)(sm + byte) = *(const uint2*)p;
        }
    __syncthreads();

    char* dst = (char*)yT + ((size_t)(b * 256 + i) * 256 + j0) * 128;  // *64ch*2B
#pragma unroll
    for (int k = 0; k < 4; ++k) {
        int u = k * 256 + tid;                     // 1024 units of 16B
        int col = u >> 3, ch = u & 7;
        int byte = (col << 7) + ((ch ^ (col & 7)) << 4);
        *(uint4*)(dst + (size_t)u * 16) = *(const uint4*)(sm + byte);
    }
}

// ---------------------------------------------------------------------------
// Pass 3: yT -> out NCHW fp32. Block = 16 j x 16 groups of 4 ch; wave-0
// precomputed weights/offsets; padded-LDS bounce [16][65] -> 64B-contiguous
// nt-store segments per channel plane.
// ---------------------------------------------------------------------------
__global__ __launch_bounds__(256)
void k_lp2c(const unsigned short* __restrict__ yT, float* __restrict__ out,
            float gx_scale, float gy_scale) {
    __shared__ float smc[16 * 65];         // [jl][ch], pad 65
    __shared__ alignas(16) float sw[16][4];
    __shared__ alignas(16) int   so[16][4];
    const int tid = threadIdx.x;
    const int g   = tid & 15;              // channel group (4 ch)
    const int jl  = tid >> 4;              // 0..15
    const int j0  = blockIdx.x * 16;
    const int i   = blockIdx.y;
    const int b   = blockIdx.z;
    const int c0  = g * 4;

    if (tid < 16) {
        float X = (float)(j0 + tid) - 127.5f;
        float Y = (float)i - 127.5f;
        float R = sqrtf(X * X + Y * Y);
        float Th = atan2f(Y, X + EPSF);
        if (Th < 0.0f) Th += 6.2831853071795864769f;
        float gx = logf(R + EPSF) * gx_scale;
        float gy = Th * gy_scale;
        float left = floorf(gx), top = floorf(gy);
        int li = (int)left, ti = (int)top, ri = li + 1, bi = ti + 1;
        float dl = gx - left, dr = left + 1.0f - gx;
        float dt = gy - top,  db = top + 1.0f - gy;
        bool vl = (unsigned)li < (unsigned)WN, vr = (unsigned)ri < (unsigned)WN;
        bool vt = (unsigned)ti < (unsigned)HN, vb = (unsigned)bi < (unsigned)HN;
        bool v0 = vl && vt, v1 = vr && vt, v2 = vl && vb, v3 = vr && vb;
        sw[tid][0] = v0 ? db * dr : 0.0f;
        sw[tid][1] = v1 ? db * dl : 0.0f;
        sw[tid][2] = v2 ? dt * dr : 0.0f;
        sw[tid][3] = v3 ? dt * dl : 0.0f;
        so[tid][0] = v0 ? (ti * WN + li) * CN : 0;
        so[tid][1] = v1 ? (ti * WN + ri) * CN : 0;
        so[tid][2] = v2 ? (bi * WN + li) * CN : 0;
        so[tid][3] = v3 ? (bi * WN + ri) * CN : 0;
    }
    __syncthreads();
    f32x4 w4 = *(const f32x4*)sw[jl];
    int4  o4 = *(const int4*)so[jl];

    const unsigned short* yb = yT + (size_t)b * IMG * CN + c0;
    union U4 { uint2 u; unsigned short s[4]; };
    U4 tl, tr, bl, br;
    tl.u = *(const uint2*)(yb + o4.x);
    tr.u = *(const uint2*)(yb + o4.y);
    bl.u = *(const uint2*)(yb + o4.z);
    br.u = *(const uint2*)(yb + o4.w);

#pragma unroll
    for (int e = 0; e < 4; ++e) {
        float v = w4[0] * bf2f(tl.s[e]) + w4[1] * bf2f(tr.s[e])
                + w4[2] * bf2f(bl.s[e]) + w4[3] * bf2f(br.s[e]);
        smc[jl * 65 + c0 + e] = v;
    }
    __syncthreads();

#pragma unroll
    for (int k = 0; k < 4; ++k) {
        int idx = k * 256 + tid;           // 0..1023
        int ch  = idx >> 4;                // 0..63
        int jr  = idx & 15;
        float v = smc[jr * 65 + ch];
        __builtin_nontemporal_store(
            v, out + ((size_t)(b * CN + ch)) * IMG + i * WN + j0 + jr);
    }
}

// ---------------------------------------------------------------------------
extern "C" void kernel_launch(void* const* d_in, const int* in_sizes, int n_in,
                              void* d_out, int out_size, void* d_ws, size_t ws_size,
                              hipStream_t stream) {
    const float* x    = (const float*)d_in[0];
    const float* wgt  = (const float*)d_in[1];
    const float* bias = (const float*)d_in[2];

    // log-polar params (double precision on host, truncated to f32)
    const double cx = (WN - 1) / 2.0;
    const double xm = WN - cx;                    // 128.5
    const double rmax = sqrt(2.0 * xm * xm);
    const double lrm = log(rmax + 0.001);
    const float lr_scale = (float)(lrm / WN);
    const float th_scale = (float)(2.0 * M_PI / HN);
    const float gx_scale = (float)(WN / lrm);
    const float gy_scale = (float)(HN / (2.0 * M_PI));

    const size_t half = (size_t)BN * HN * WN * CN * 2;       // 128 MB bf16
    unsigned short* lpT = (unsigned short*)d_ws;
    unsigned short* yT  = (unsigned short*)((char*)d_ws + half);
    // d_out (256 MB) doubles as scratch until the final pass:
    unsigned short* xT  = (unsigned short*)d_out;            // 128 MB
    unsigned short* wp  = (unsigned short*)((char*)d_out + half);  // 72 KB

    dim3 blk(256, 1, 1);

    k_wprep<<<dim3(144, 1, 1), blk, 0, stream>>>(wgt, wp);
    k_xpose<<<dim3(HN, BN, 1), blk, 0, stream>>>(x, xT);
    k_c2lp <<<dim3(WN / 16, HN, BN), blk, 0, stream>>>(xT, lpT, lr_scale, th_scale);
    k_conv <<<dim3(8192, 1, 1), blk, 0, stream>>>(lpT, wp, bias, yT);
    k_lp2c <<<dim3(WN / 16, HN, BN), blk, 0, stream>>>(yT, (float*)d_out, gx_scale, gy_scale);
}

// Round 15
// 366.808 us; speedup vs baseline: 1.1137x; 1.1137x over previous
//
#include <hip/hip_runtime.h>
#include <cmath>

constexpr int BN = 16, CN = 64, HN = 256, WN = 256;
constexpr int IMG = HN * WN;
constexpr float EPSF = 0.001f;

typedef short bf16x8 __attribute__((ext_vector_type(8)));
typedef float f32x4  __attribute__((ext_vector_type(4)));

// ---- bf16 helpers (RNE, finite inputs) ------------------------------------
__device__ __forceinline__ unsigned short f2bf(float f) {
    unsigned u = __builtin_bit_cast(unsigned, f);
    u += 0x7fffu + ((u >> 16) & 1u);
    return (unsigned short)(u >> 16);
}
__device__ __forceinline__ float bf2f(unsigned short h) {
    return __builtin_bit_cast(float, ((unsigned)h) << 16);
}

__device__ __forceinline__ void gload16(const void* g, void* l) {
    __builtin_amdgcn_global_load_lds(
        (const __attribute__((address_space(1))) unsigned int*)g,
        (__attribute__((address_space(3))) unsigned int*)l, 16, 0, 0);
}

// ---------------------------------------------------------------------------
// Weight prep: W[co][ci][3][3] fp32 -> bf16 MFMA A-fragments
// ---------------------------------------------------------------------------
__global__ __launch_bounds__(256)
void k_wprep(const float* __restrict__ w, unsigned short* __restrict__ wp) {
    int flat = blockIdx.x * 256 + threadIdx.x;       // 0..36863
    int ct = flat / 9216;
    int r1 = flat % 9216;
    int s  = r1 / 1024;
    int r2 = r1 % 1024;
    int kk = r2 >> 9;
    int l  = (r2 >> 3) & 63;
    int e  = r2 & 7;
    int co = ct * 16 + (l & 15);
    int ci = kk * 32 + (l >> 4) * 8 + e;
    int kh = s / 3, kw = s % 3;
    wp[flat] = f2bf(w[((co * 64 + ci) * 3 + kh) * 3 + kw]);
}

// ---------------------------------------------------------------------------
// Pass 0: x[b][c][i][j] fp32 -> xT[b][i][j][c] bf16  (pure layout transpose)
// ---------------------------------------------------------------------------
__global__ __launch_bounds__(256)
void k_xpose(const float* __restrict__ x, unsigned short* __restrict__ xT) {
    __shared__ alignas(16) unsigned char sm[WN * CN * 2];   // 32 KB [j][c]
    const int j = threadIdx.x;
    const int i = blockIdx.x;
    const int b = blockIdx.y;
    const float* xb = x + (size_t)b * CN * IMG + (size_t)i * WN + j;
#pragma unroll 2
    for (int c0 = 0; c0 < CN; c0 += 8) {
        unsigned short p[8];
#pragma unroll
        for (int e = 0; e < 8; ++e)
            p[e] = f2bf(xb[(size_t)(c0 + e) * IMG]);
        int byte = (j << 7) + (c0 << 1);
        byte ^= (j & 7) << 4;                 // bank swizzle
        *(uint4*)(sm + byte) = *(const uint4*)p;
    }
    __syncthreads();
    char* dst = (char*)xT + (size_t)(b * HN + i) * (WN * CN * 2);
#pragma unroll
    for (int k = 0; k < 8; ++k) {
        int u = k * 256 + threadIdx.x;
        int jj = u >> 3, ch = u & 7;
        int byte = (jj << 7) + ((ch ^ (jj & 7)) << 4);
        *(uint4*)(dst + (size_t)u * 16) = *(const uint4*)(sm + byte);
    }
}

// ---------------------------------------------------------------------------
// Pass 1: xT -> lpT (log-polar gather). Block = 16 j x 16 groups of 4 ch.
// Wave 0 precomputes per-pixel bilinear weights (validity folded) + offsets.
// ---------------------------------------------------------------------------
__global__ __launch_bounds__(256)
void k_c2lp(const unsigned short* __restrict__ xT, unsigned short* __restrict__ lpT,
            float lr_scale, float th_scale) {
    __shared__ alignas(16) float sw[16][4];
    __shared__ alignas(16) int   so[16][4];
    const int tid = threadIdx.x;
    const int g   = tid & 15;              // channel group (4 ch)
    const int jl  = tid >> 4;              // 0..15
    const int j0  = blockIdx.x * 16;
    const int j   = j0 + jl;
    const int i   = blockIdx.y;
    const int b   = blockIdx.z;
    const int c0  = g * 4;

    if (tid < 16) {
        float r  = __expf((float)(j0 + tid) * lr_scale);
        float th = (float)i * th_scale;
        float gx = fmaf(r, cosf(th), 127.5f);
        float gy = fmaf(r, sinf(th), 127.5f);
        float left = floorf(gx), top = floorf(gy);
        int li = (int)left, ti = (int)top, ri = li + 1, bi = ti + 1;
        float dl = gx - left, dr = left + 1.0f - gx;
        float dt = gy - top,  db = top + 1.0f - gy;
        bool vl = (unsigned)li < (unsigned)WN, vr = (unsigned)ri < (unsigned)WN;
        bool vt = (unsigned)ti < (unsigned)HN, vb = (unsigned)bi < (unsigned)HN;
        bool v0 = vl && vt, v1 = vr && vt, v2 = vl && vb, v3 = vr && vb;
        sw[tid][0] = v0 ? db * dr : 0.0f;
        sw[tid][1] = v1 ? db * dl : 0.0f;
        sw[tid][2] = v2 ? dt * dr : 0.0f;
        sw[tid][3] = v3 ? dt * dl : 0.0f;
        so[tid][0] = v0 ? (ti * WN + li) * CN : 0;
        so[tid][1] = v1 ? (ti * WN + ri) * CN : 0;
        so[tid][2] = v2 ? (bi * WN + li) * CN : 0;
        so[tid][3] = v3 ? (bi * WN + ri) * CN : 0;
    }
    __syncthreads();
    f32x4 w4 = *(const f32x4*)sw[jl];
    int4  o4 = *(const int4*)so[jl];

    const unsigned short* yb = xT + (size_t)b * IMG * CN + c0;
    union U4 { uint2 u; unsigned short s[4]; };
    U4 tl, tr, bl, br;
    tl.u = *(const uint2*)(yb + o4.x);
    tr.u = *(const uint2*)(yb + o4.y);
    bl.u = *(const uint2*)(yb + o4.z);
    br.u = *(const uint2*)(yb + o4.w);

    U4 res;
#pragma unroll
    for (int e = 0; e < 4; ++e) {
        float v = w4[0] * bf2f(tl.s[e]) + w4[1] * bf2f(tr.s[e])
                + w4[2] * bf2f(bl.s[e]) + w4[3] * bf2f(br.s[e]);
        res.s[e] = f2bf(v);
    }
    *(uint2*)(lpT + ((size_t)(b * HN + i) * WN + j) * CN + c0) = res.u;
}

// ---------------------------------------------------------------------------
// Pass 2: MFMA conv. block = (b, i, 128 cols) x 64 co, 4 waves (r13 exact).
// Wave w owns cols [(w&1)*64,+64) x co [(w>>1)*32,+32): each B ds_read feeds
// 2 MFMAs. LDS stage [3][130][64] bf16, XOR-swizzled 16B chunks.
// ---------------------------------------------------------------------------
__global__ __launch_bounds__(256)
void k_conv(const unsigned short* __restrict__ lpT,
            const unsigned short* __restrict__ wp,
            const float* __restrict__ bias,
            unsigned short* __restrict__ yT) {
    __shared__ alignas(16) unsigned char sm[3 * 130 * 64 * 2];   // 49920 B
    const int tid = threadIdx.x;
    const int w = tid >> 6, lane = tid & 63;
    const int lanelo = lane & 15, lanehi = lane >> 4;
    const int wcol = (w & 1) * 64;        // this wave's column half
    const int wco  = (w >> 1) * 2;        // this wave's first co-tile (of 16 co)
    const int j0 = blockIdx.x * 128;
    const int i  = blockIdx.y;
    const int b  = blockIdx.z;

    // ---- stage 3 rows x 130 cols x 64 ci (3120 16B units) ----
    for (int u0 = 0; u0 < 3120; u0 += 256) {
        int unit = u0 + tid;
        if (unit < 3120) {
            int r   = unit / 1040;
            int rem = unit - r * 1040;
            int col = rem >> 3, ch = rem & 7;
            int ii = i - 1 + r;
            int jj = j0 - 1 + col;
            void* lptr = sm + unit * 16;
            if ((unsigned)ii < 256u && (unsigned)jj < 256u) {
                int sch = ch ^ (col & 7);        // pre-swizzled source
                const unsigned short* g =
                    lpT + (((size_t)(b * 256 + ii) * 256 + jj) * 64 + sch * 8);
                gload16(g, lptr);
            } else {
                uint4 z; z.x = z.y = z.z = z.w = 0;
                *(uint4*)lptr = z;
            }
        }
    }

    // ---- weights: 2 co-tiles x 18 A-fragments ----
    bf16x8 af[2][18];
#pragma unroll
    for (int m = 0; m < 2; ++m)
#pragma unroll
        for (int sk = 0; sk < 18; ++sk)
            af[m][sk] = *(const bf16x8*)(
                wp + ((size_t)((wco + m) * 18 + sk) * 64 + lane) * 8);

    // ---- accumulators (2 co-tiles x 4 col-frags), init with bias ----
    f32x4 acc[2][4];
#pragma unroll
    for (int m = 0; m < 2; ++m) {
        int co_row = (wco + m) * 16 + lanehi * 4;
        f32x4 binit = { bias[co_row], bias[co_row + 1],
                        bias[co_row + 2], bias[co_row + 3] };
#pragma unroll
        for (int n = 0; n < 4; ++n) acc[m][n] = binit;
    }

    __syncthreads();

    // ---- 9 shifts x 2 K-steps x 4 col-frags; each B read feeds 2 MFMAs ----
#pragma unroll
    for (int s = 0; s < 9; ++s) {
        const int kh = s / 3, kw = s % 3;
#pragma unroll
        for (int kk = 0; kk < 2; ++kk) {
            const int cih = kk * 4 + lanehi;        // ci>>3
#pragma unroll
            for (int n = 0; n < 4; ++n) {
                int col  = wcol + n * 16 + lanelo + kw;    // 0..129
                int unit = (kh * 130 + col) * 8 + (cih ^ (col & 7));
                bf16x8 bf = *(const bf16x8*)(sm + unit * 16);
                acc[0][n] = __builtin_amdgcn_mfma_f32_16x16x32_bf16(
                    af[0][s * 2 + kk], bf, acc[0][n], 0, 0, 0);
                acc[1][n] = __builtin_amdgcn_mfma_f32_16x16x32_bf16(
                    af[1][s * 2 + kk], bf, acc[1][n], 0, 0, 0);
            }
        }
    }

    __syncthreads();    // all ds_reads done; reuse sm for out tile [128][64] bf16

#pragma unroll
    for (int m = 0; m < 2; ++m)
#pragma unroll
        for (int n = 0; n < 4; ++n) {
            int col = wcol + n * 16 + lanelo;
            int co  = (wco + m) * 16 + lanehi * 4;
            unsigned short p[4];
#pragma unroll
            for (int r = 0; r < 4; ++r) p[r] = f2bf(acc[m][n][r]);
            int byte = (col << 7) + (co << 1);
            byte ^= (col & 7) << 4;
            *(uint2*)(sm + byte) = *(const uint2*)p;
        }
    __syncthreads();

    char* dst = (char*)yT + ((size_t)(b * 256 + i) * 256 + j0) * 128;  // *64ch*2B
#pragma unroll
    for (int k = 0; k < 4; ++k) {
        int u = k * 256 + tid;                     // 1024 units of 16B
        int col = u >> 3, ch = u & 7;
        int byte = (col << 7) + ((ch ^ (col & 7)) << 4);
        *(uint4*)(dst + (size_t)u * 16) = *(const uint4*)(sm + byte);
    }
}

// ---------------------------------------------------------------------------
// Pass 3: yT -> out NCHW fp32. Block = 512 threads: 32 j x 16 groups of 4 ch.
// Wave-0 pair (tid<32) precomputes weights/offsets; bounce [32][65] f32;
// readout = 128B-contiguous nt-store segments per channel plane.
// ---------------------------------------------------------------------------
__global__ __launch_bounds__(512)
void k_lp2c(const unsigned short* __restrict__ yT, float* __restrict__ out,
            float gx_scale, float gy_scale) {
    __shared__ float smc[32 * 65];         // [jl][ch], pad 65
    __shared__ alignas(16) float sw[32][4];
    __shared__ alignas(16) int   so[32][4];
    const int tid = threadIdx.x;
    const int g   = tid & 15;              // channel group (4 ch)
    const int jl  = tid >> 4;              // 0..31
    const int j0  = blockIdx.x * 32;
    const int i   = blockIdx.y;
    const int b   = blockIdx.z;
    const int c0  = g * 4;

    if (tid < 32) {
        float X = (float)(j0 + tid) - 127.5f;
        float Y = (float)i - 127.5f;
        float R = sqrtf(X * X + Y * Y);
        float Th = atan2f(Y, X + EPSF);
        if (Th < 0.0f) Th += 6.2831853071795864769f;
        float gx = logf(R + EPSF) * gx_scale;
        float gy = Th * gy_scale;
        float left = floorf(gx), top = floorf(gy);
        int li = (int)left, ti = (int)top, ri = li + 1, bi = ti + 1;
        float dl = gx - left, dr = left + 1.0f - gx;
        float dt = gy - top,  db = top + 1.0f - gy;
        bool vl = (unsigned)li < (unsigned)WN, vr = (unsigned)ri < (unsigned)WN;
        bool vt = (unsigned)ti < (unsigned)HN, vb = (unsigned)bi < (unsigned)HN;
        bool v0 = vl && vt, v1 = vr && vt, v2 = vl && vb, v3 = vr && vb;
        sw[tid][0] = v0 ? db * dr : 0.0f;
        sw[tid][1] = v1 ? db * dl : 0.0f;
        sw[tid][2] = v2 ? dt * dr : 0.0f;
        sw[tid][3] = v3 ? dt * dl : 0.0f;
        so[tid][0] = v0 ? (ti * WN + li) * CN : 0;
        so[tid][1] = v1 ? (ti * WN + ri) * CN : 0;
        so[tid][2] = v2 ? (bi * WN + li) * CN : 0;
        so[tid][3] = v3 ? (bi * WN + ri) * CN : 0;
    }
    __syncthreads();
    f32x4 w4 = *(const f32x4*)sw[jl];
    int4  o4 = *(const int4*)so[jl];

    const unsigned short* yb = yT + (size_t)b * IMG * CN + c0;
    union U4 { uint2 u; unsigned short s[4]; };
    U4 tl, tr, bl, br;
    tl.u = *(const uint2*)(yb + o4.x);
    tr.u = *(const uint2*)(yb + o4.y);
    bl.u = *(const uint2*)(yb + o4.z);
    br.u = *(const uint2*)(yb + o4.w);

#pragma unroll
    for (int e = 0; e < 4; ++e) {
        float v = w4[0] * bf2f(tl.s[e]) + w4[1] * bf2f(tr.s[e])
                + w4[2] * bf2f(bl.s[e]) + w4[3] * bf2f(br.s[e]);
        smc[jl * 65 + c0 + e] = v;
    }
    __syncthreads();

#pragma unroll
    for (int k = 0; k < 4; ++k) {
        int idx = k * 512 + tid;           // 0..2047
        int ch  = idx >> 5;                // 0..63
        int jr  = idx & 31;
        float v = smc[jr * 65 + ch];
        __builtin_nontemporal_store(
            v, out + ((size_t)(b * CN + ch)) * IMG + i * WN + j0 + jr);
    }
}

// ---------------------------------------------------------------------------
extern "C" void kernel_launch(void* const* d_in, const int* in_sizes, int n_in,
                              void* d_out, int out_size, void* d_ws, size_t ws_size,
                              hipStream_t stream) {
    const float* x    = (const float*)d_in[0];
    const float* wgt  = (const float*)d_in[1];
    const float* bias = (const float*)d_in[2];

    // log-polar params (double precision on host, truncated to f32)
    const double cx = (WN - 1) / 2.0;
    const double xm = WN - cx;                    // 128.5
    const double rmax = sqrt(2.0 * xm * xm);
    const double lrm = log(rmax + 0.001);
    const float lr_scale = (float)(lrm / WN);
    const float th_scale = (float)(2.0 * M_PI / HN);
    const float gx_scale = (float)(WN / lrm);
    const float gy_scale = (float)(HN / (2.0 * M_PI));

    const size_t half = (size_t)BN * HN * WN * CN * 2;       // 128 MB bf16
    unsigned short* lpT = (unsigned short*)d_ws;
    unsigned short* yT  = (unsigned short*)((char*)d_ws + half);
    // d_out (256 MB) doubles as scratch until the final pass:
    unsigned short* xT  = (unsigned short*)d_out;            // 128 MB
    unsigned short* wp  = (unsigned short*)((char*)d_out + half);  // 72 KB

    dim3 blk(256, 1, 1);

    k_wprep<<<dim3(144, 1, 1), blk, 0, stream>>>(wgt, wp);
    k_xpose<<<dim3(HN, BN, 1), blk, 0, stream>>>(x, xT);
    k_c2lp <<<dim3(WN / 16, HN, BN), blk, 0, stream>>>(xT, lpT, lr_scale, th_scale);
    k_conv <<<dim3(WN / 128, HN, BN), blk, 0, stream>>>(lpT, wp, bias, yT);
    k_lp2c <<<dim3(WN / 32, HN, BN), dim3(512, 1, 1), 0, stream>>>(
        yT, (float*)d_out, gx_scale, gy_scale);
}

// Round 17
// 366.020 us; speedup vs baseline: 1.1161x; 1.0022x over previous
//
#include <hip/hip_runtime.h>
#include <cmath>

constexpr int BN = 16, CN = 64, HN = 256, WN = 256;
constexpr int IMG = HN * WN;
constexpr float EPSF = 0.001f;

typedef short bf16x8 __attribute__((ext_vector_type(8)));
typedef float f32x4  __attribute__((ext_vector_type(4)));

// ---- bf16 helpers (RNE, finite inputs) ------------------------------------
__device__ __forceinline__ unsigned short f2bf(float f) {
    unsigned u = __builtin_bit_cast(unsigned, f);
    u += 0x7fffu + ((u >> 16) & 1u);
    return (unsigned short)(u >> 16);
}
__device__ __forceinline__ float bf2f(unsigned short h) {
    return __builtin_bit_cast(float, ((unsigned)h) << 16);
}

__device__ __forceinline__ void gload16(const void* g, void* l) {
    __builtin_amdgcn_global_load_lds(
        (const __attribute__((address_space(1))) unsigned int*)g,
        (__attribute__((address_space(3))) unsigned int*)l, 16, 0, 0);
}

// ---------------------------------------------------------------------------
// Weight prep: W[co][ci][3][3] fp32 -> bf16 MFMA A-fragments
// ---------------------------------------------------------------------------
__global__ __launch_bounds__(256)
void k_wprep(const float* __restrict__ w, unsigned short* __restrict__ wp) {
    int flat = blockIdx.x * 256 + threadIdx.x;       // 0..36863
    int ct = flat / 9216;
    int r1 = flat % 9216;
    int s  = r1 / 1024;
    int r2 = r1 % 1024;
    int kk = r2 >> 9;
    int l  = (r2 >> 3) & 63;
    int e  = r2 & 7;
    int co = ct * 16 + (l & 15);
    int ci = kk * 32 + (l >> 4) * 8 + e;
    int kh = s / 3, kw = s % 3;
    wp[flat] = f2bf(w[((co * 64 + ci) * 3 + kh) * 3 + kw]);
}

// ---------------------------------------------------------------------------
// Pass 0: x[b][c][i][j] fp32 -> xT[b][i][j][c] bf16  (pure layout transpose)
// ---------------------------------------------------------------------------
__global__ __launch_bounds__(256)
void k_xpose(const float* __restrict__ x, unsigned short* __restrict__ xT) {
    __shared__ alignas(16) unsigned char sm[WN * CN * 2];   // 32 KB [j][c]
    const int j = threadIdx.x;
    const int i = blockIdx.x;
    const int b = blockIdx.y;
    const float* xb = x + (size_t)b * CN * IMG + (size_t)i * WN + j;
#pragma unroll 2
    for (int c0 = 0; c0 < CN; c0 += 8) {
        unsigned short p[8];
#pragma unroll
        for (int e = 0; e < 8; ++e)
            p[e] = f2bf(xb[(size_t)(c0 + e) * IMG]);
        int byte = (j << 7) + (c0 << 1);
        byte ^= (j & 7) << 4;                 // bank swizzle
        *(uint4*)(sm + byte) = *(const uint4*)p;
    }
    __syncthreads();
    char* dst = (char*)xT + (size_t)(b * HN + i) * (WN * CN * 2);
#pragma unroll
    for (int k = 0; k < 8; ++k) {
        int u = k * 256 + threadIdx.x;
        int jj = u >> 3, ch = u & 7;
        int byte = (jj << 7) + ((ch ^ (jj & 7)) << 4);
        *(uint4*)(dst + (size_t)u * 16) = *(const uint4*)(sm + byte);
    }
}

// ---------------------------------------------------------------------------
// Pass 1: xT -> lpT (log-polar gather). Block = 512 threads: 32 j x 16
// groups of 4 ch. Wave-0 pair (tid<32) precomputes per-pixel bilinear
// weights (validity folded) + offsets into LDS.
// ---------------------------------------------------------------------------
__global__ __launch_bounds__(512)
void k_c2lp(const unsigned short* __restrict__ xT, unsigned short* __restrict__ lpT,
            float lr_scale, float th_scale) {
    __shared__ alignas(16) float sw[32][4];
    __shared__ alignas(16) int   so[32][4];
    const int tid = threadIdx.x;
    const int g   = tid & 15;              // channel group (4 ch)
    const int jl  = tid >> 4;              // 0..31
    const int j0  = blockIdx.x * 32;
    const int j   = j0 + jl;
    const int i   = blockIdx.y;
    const int b   = blockIdx.z;
    const int c0  = g * 4;

    if (tid < 32) {
        float r  = __expf((float)(j0 + tid) * lr_scale);
        float th = (float)i * th_scale;
        float gx = fmaf(r, cosf(th), 127.5f);
        float gy = fmaf(r, sinf(th), 127.5f);
        float left = floorf(gx), top = floorf(gy);
        int li = (int)left, ti = (int)top, ri = li + 1, bi = ti + 1;
        float dl = gx - left, dr = left + 1.0f - gx;
        float dt = gy - top,  db = top + 1.0f - gy;
        bool vl = (unsigned)li < (unsigned)WN, vr = (unsigned)ri < (unsigned)WN;
        bool vt = (unsigned)ti < (unsigned)HN, vb = (unsigned)bi < (unsigned)HN;
        bool v0 = vl && vt, v1 = vr && vt, v2 = vl && vb, v3 = vr && vb;
        sw[tid][0] = v0 ? db * dr : 0.0f;
        sw[tid][1] = v1 ? db * dl : 0.0f;
        sw[tid][2] = v2 ? dt * dr : 0.0f;
        sw[tid][3] = v3 ? dt * dl : 0.0f;
        so[tid][0] = v0 ? (ti * WN + li) * CN : 0;
        so[tid][1] = v1 ? (ti * WN + ri) * CN : 0;
        so[tid][2] = v2 ? (bi * WN + li) * CN : 0;
        so[tid][3] = v3 ? (bi * WN + ri) * CN : 0;
    }
    __syncthreads();
    f32x4 w4 = *(const f32x4*)sw[jl];
    int4  o4 = *(const int4*)so[jl];

    const unsigned short* yb = xT + (size_t)b * IMG * CN + c0;
    union U4 { uint2 u; unsigned short s[4]; };
    U4 tl, tr, bl, br;
    tl.u = *(const uint2*)(yb + o4.x);
    tr.u = *(const uint2*)(yb + o4.y);
    bl.u = *(const uint2*)(yb + o4.z);
    br.u = *(const uint2*)(yb + o4.w);

    U4 res;
#pragma unroll
    for (int e = 0; e < 4; ++e) {
        float v = w4[0] * bf2f(tl.s[e]) + w4[1] * bf2f(tr.s[e])
                + w4[2] * bf2f(bl.s[e]) + w4[3] * bf2f(br.s[e]);
        res.s[e] = f2bf(v);
    }
    *(uint2*)(lpT + ((size_t)(b * HN + i) * WN + j) * CN + c0) = res.u;
}

// ---------------------------------------------------------------------------
// Pass 2: MFMA conv. block = (b, i, 128 cols) x 64 co, 4 waves (r13 exact).
// Wave w owns cols [(w&1)*64,+64) x co [(w>>1)*32,+32): each B ds_read feeds
// 2 MFMAs. LDS stage [3][130][64] bf16, XOR-swizzled 16B chunks.
// ---------------------------------------------------------------------------
__global__ __launch_bounds__(256)
void k_conv(const unsigned short* __restrict__ lpT,
            const unsigned short* __restrict__ wp,
            const float* __restrict__ bias,
            unsigned short* __restrict__ yT) {
    __shared__ alignas(16) unsigned char sm[3 * 130 * 64 * 2];   // 49920 B
    const int tid = threadIdx.x;
    const int w = tid >> 6, lane = tid & 63;
    const int lanelo = lane & 15, lanehi = lane >> 4;
    const int wcol = (w & 1) * 64;        // this wave's column half
    const int wco  = (w >> 1) * 2;        // this wave's first co-tile (of 16 co)
    const int j0 = blockIdx.x * 128;
    const int i  = blockIdx.y;
    const int b  = blockIdx.z;

    // ---- stage 3 rows x 130 cols x 64 ci (3120 16B units) ----
    for (int u0 = 0; u0 < 3120; u0 += 256) {
        int unit = u0 + tid;
        if (unit < 3120) {
            int r   = unit / 1040;
            int rem = unit - r * 1040;
            int col = rem >> 3, ch = rem & 7;
            int ii = i - 1 + r;
            int jj = j0 - 1 + col;
            void* lptr = sm + unit * 16;
            if ((unsigned)ii < 256u && (unsigned)jj < 256u) {
                int sch = ch ^ (col & 7);        // pre-swizzled source
                const unsigned short* g =
                    lpT + (((size_t)(b * 256 + ii) * 256 + jj) * 64 + sch * 8);
                gload16(g, lptr);
            } else {
                uint4 z; z.x = z.y = z.z = z.w = 0;
                *(uint4*)lptr = z;
            }
        }
    }

    // ---- weights: 2 co-tiles x 18 A-fragments ----
    bf16x8 af[2][18];
#pragma unroll
    for (int m = 0; m < 2; ++m)
#pragma unroll
        for (int sk = 0; sk < 18; ++sk)
            af[m][sk] = *(const bf16x8*)(
                wp + ((size_t)((wco + m) * 18 + sk) * 64 + lane) * 8);

    // ---- accumulators (2 co-tiles x 4 col-frags), init with bias ----
    f32x4 acc[2][4];
#pragma unroll
    for (int m = 0; m < 2; ++m) {
        int co_row = (wco + m) * 16 + lanehi * 4;
        f32x4 binit = { bias[co_row], bias[co_row + 1],
                        bias[co_row + 2], bias[co_row + 3] };
#pragma unroll
        for (int n = 0; n < 4; ++n) acc[m][n] = binit;
    }

    __syncthreads();

    // ---- 9 shifts x 2 K-steps x 4 col-frags; each B read feeds 2 MFMAs ----
#pragma unroll
    for (int s = 0; s < 9; ++s) {
        const int kh = s / 3, kw = s % 3;
#pragma unroll
        for (int kk = 0; kk < 2; ++kk) {
            const int cih = kk * 4 + lanehi;        // ci>>3
#pragma unroll
            for (int n = 0; n < 4; ++n) {
                int col  = wcol + n * 16 + lanelo + kw;    // 0..129
                int unit = (kh * 130 + col) * 8 + (cih ^ (col & 7));
                bf16x8 bf = *(const bf16x8*)(sm + unit * 16);
                acc[0][n] = __builtin_amdgcn_mfma_f32_16x16x32_bf16(
                    af[0][s * 2 + kk], bf, acc[0][n], 0, 0, 0);
                acc[1][n] = __builtin_amdgcn_mfma_f32_16x16x32_bf16(
                    af[1][s * 2 + kk], bf, acc[1][n], 0, 0, 0);
            }
        }
    }

    __syncthreads();    // all ds_reads done; reuse sm for out tile [128][64] bf16

#pragma unroll
    for (int m = 0; m < 2; ++m)
#pragma unroll
        for (int n = 0; n < 4; ++n) {
            int col = wcol + n * 16 + lanelo;
            int co  = (wco + m) * 16 + lanehi * 4;
            unsigned short p[4];
#pragma unroll
            for (int r = 0; r < 4; ++r) p[r] = f2bf(acc[m][n][r]);
            int byte = (col << 7) + (co << 1);
            byte ^= (col & 7) << 4;
            *(uint2*)(sm + byte) = *(const uint2*)p;
        }
    __syncthreads();

    char* dst = (char*)yT + ((size_t)(b * 256 + i) * 256 + j0) * 128;  // *64ch*2B
#pragma unroll
    for (int k = 0; k < 4; ++k) {
        int u = k * 256 + tid;                     // 1024 units of 16B
        int col = u >> 3, ch = u & 7;
        int byte = (col << 7) + ((ch ^ (col & 7)) << 4);
        *(uint4*)(dst + (size_t)u * 16) = *(const uint4*)(sm + byte);
    }
}

// ---------------------------------------------------------------------------
// Pass 3: yT -> out NCHW fp32. Block = 512 threads: 32 j x 16 groups of 4 ch.
// Wave-0 pair (tid<32) precomputes weights/offsets; bounce [32][65] f32;
// readout = 128B-contiguous nt-store segments per channel plane.
// ---------------------------------------------------------------------------
__global__ __launch_bounds__(512)
void k_lp2c(const unsigned short* __restrict__ yT, float* __restrict__ out,
            float gx_scale, float gy_scale) {
    __shared__ float smc[32 * 65];         // [jl][ch], pad 65
    __shared__ alignas(16) float sw[32][4];
    __shared__ alignas(16) int   so[32][4];
    const int tid = threadIdx.x;
    const int g   = tid & 15;              // channel group (4 ch)
    const int jl  = tid >> 4;              // 0..31
    const int j0  = blockIdx.x * 32;
    const int i   = blockIdx.y;
    const int b   = blockIdx.z;
    const int c0  = g * 4;

    if (tid < 32) {
        float X = (float)(j0 + tid) - 127.5f;
        float Y = (float)i - 127.5f;
        float R = sqrtf(X * X + Y * Y);
        float Th = atan2f(Y, X + EPSF);
        if (Th < 0.0f) Th += 6.2831853071795864769f;
        float gx = logf(R + EPSF) * gx_scale;
        float gy = Th * gy_scale;
        float left = floorf(gx), top = floorf(gy);
        int li = (int)left, ti = (int)top, ri = li + 1, bi = ti + 1;
        float dl = gx - left, dr = left + 1.0f - gx;
        float dt = gy - top,  db = top + 1.0f - gy;
        bool vl = (unsigned)li < (unsigned)WN, vr = (unsigned)ri < (unsigned)WN;
        bool vt = (unsigned)ti < (unsigned)HN, vb = (unsigned)bi < (unsigned)HN;
        bool v0 = vl && vt, v1 = vr && vt, v2 = vl && vb, v3 = vr && vb;
        sw[tid][0] = v0 ? db * dr : 0.0f;
        sw[tid][1] = v1 ? db * dl : 0.0f;
        sw[tid][2] = v2 ? dt * dr : 0.0f;
        sw[tid][3] = v3 ? dt * dl : 0.0f;
        so[tid][0] = v0 ? (ti * WN + li) * CN : 0;
        so[tid][1] = v1 ? (ti * WN + ri) * CN : 0;
        so[tid][2] = v2 ? (bi * WN + li) * CN : 0;
        so[tid][3] = v3 ? (bi * WN + ri) * CN : 0;
    }
    __syncthreads();
    f32x4 w4 = *(const f32x4*)sw[jl];
    int4  o4 = *(const int4*)so[jl];

    const unsigned short* yb = yT + (size_t)b * IMG * CN + c0;
    union U4 { uint2 u; unsigned short s[4]; };
    U4 tl, tr, bl, br;
    tl.u = *(const uint2*)(yb + o4.x);
    tr.u = *(const uint2*)(yb + o4.y);
    bl.u = *(const uint2*)(yb + o4.z);
    br.u = *(const uint2*)(yb + o4.w);

#pragma unroll
    for (int e = 0; e < 4; ++e) {
        float v = w4[0] * bf2f(tl.s[e]) + w4[1] * bf2f(tr.s[e])
                + w4[2] * bf2f(bl.s[e]) + w4[3] * bf2f(br.s[e]);
        smc[jl * 65 + c0 + e] = v;
    }
    __syncthreads();

#pragma unroll
    for (int k = 0; k < 4; ++k) {
        int idx = k * 512 + tid;           // 0..2047
        int ch  = idx >> 5;                // 0..63
        int jr  = idx & 31;
        float v = smc[jr * 65 + ch];
        __builtin_nontemporal_store(
            v, out + ((size_t)(b * CN + ch)) * IMG + i * WN + j0 + jr);
    }
}

// ---------------------------------------------------------------------------
extern "C" void kernel_launch(void* const* d_in, const int* in_sizes, int n_in,
                              void* d_out, int out_size, void* d_ws, size_t ws_size,
                              hipStream_t stream) {
    const float* x    = (const float*)d_in[0];
    const float* wgt  = (const float*)d_in[1];
    const float* bias = (const float*)d_in[2];

    // log-polar params (double precision on host, truncated to f32)
    const double cx = (WN - 1) / 2.0;
    const double xm = WN - cx;                    // 128.5
    const double rmax = sqrt(2.0 * xm * xm);
    const double lrm = log(rmax + 0.001);
    const float lr_scale = (float)(lrm / WN);
    const float th_scale = (float)(2.0 * M_PI / HN);
    const float gx_scale = (float)(WN / lrm);
    const float gy_scale = (float)(HN / (2.0 * M_PI));

    const size_t half = (size_t)BN * HN * WN * CN * 2;       // 128 MB bf16
    unsigned short* lpT = (unsigned short*)d_ws;
    unsigned short* yT  = (unsigned short*)((char*)d_ws + half);
    // d_out (256 MB) doubles as scratch until the final pass:
    unsigned short* xT  = (unsigned short*)d_out;            // 128 MB
    unsigned short* wp  = (unsigned short*)((char*)d_out + half);  // 72 KB

    dim3 blk(256, 1, 1);
    dim3 blk512(512, 1, 1);

    k_wprep<<<dim3(144, 1, 1), blk, 0, stream>>>(wgt, wp);
    k_xpose<<<dim3(HN, BN, 1), blk, 0, stream>>>(x, xT);
    k_c2lp <<<dim3(WN / 32, HN, BN), blk512, 0, stream>>>(xT, lpT, lr_scale, th_scale);
    k_conv <<<dim3(WN / 128, HN, BN), blk, 0, stream>>>(lpT, wp, bias, yT);
    k_lp2c <<<dim3(WN / 32, HN, BN), blk512, 0, stream>>>(yT, (float*)d_out, gx_scale, gy_scale);
}